// Round 7
// baseline (85.626 us; speedup 1.0000x reference)
//
#include <hip/hip_runtime.h>

// M[b,i,j] (16 x 256 x 256):
//   a=i>>4, c=i&15, p=j>>4, q=j&15
//   off-diag (a<p, c<q, edge(a,p) and edge(c,q) present in BOTH graphs):
//     M = P1[a,c] + P2[p,c] + P2[a,q] + P1[p,q]
//   diag (i==j): += Mp[a,c]
// P_l = F_src^T relu(lam_l+lam_l^T) F_tgt (16x16/batch), Mp = U_src^T U_tgt.
//
// SINGLE regular dispatch, grid 256 = (b, a), block 256. No ws, no grid sync:
// each block computes S_l = Fs^T W_l (W_l = relu(lam+lam^T), materialized in
// 32-row LDS chunks), then P_l = S_l Ft^T, then fills its 16 output rows.
// 16x-redundant per batch but removes the second dispatch (~10 us fixed cost).

#define LS 132   // padded stride: (132*x + j) % 32 = (4x+j)%32 -> <=2-way (free)
#define TS 17    // P-table stride
#define CH 32    // W chunk rows (4 chunks of i)

__device__ __forceinline__ int edge_idx(int a, int p) {
    // strict upper triangle of 16x16, row-major (triu_indices(16, k=1))
    return (a * (31 - a)) / 2 + (p - a - 1);
}

__global__ __launch_bounds__(256) void kOne(
    const int* __restrict__ Asrc, const int* __restrict__ Atgt,
    const float* __restrict__ Fsrc, const float* __restrict__ Ftgt,
    const float* __restrict__ Usrc, const float* __restrict__ Utgt,
    const float* __restrict__ lam1, const float* __restrict__ lam2,
    float* __restrict__ out)
{
    __shared__ float sRow1[CH * LS], sCol1[CH * LS];   // lam1 chunk rows/cols
    __shared__ float sRow2[CH * LS], sCol2[CH * LS];   // lam2 chunk rows/cols
    __shared__ float sW1[CH * LS], sW2[CH * LS];       // W chunks [il][j]
    __shared__ float sFsT[16 * LS];                    // Fs^T  [u][i]
    __shared__ float sFtT[16 * LS];                    // Ft^T  [v][j]
    __shared__ float sS1[16 * LS], sS2[16 * LS];       // S_l   [u][j]
    __shared__ float sU[512];                          // Us | Ut
    __shared__ float sP1[16 * TS], sP2[16 * TS], sMp[256];
    __shared__ int   smask[120];

    const int blk = blockIdx.x;
    const int b   = blk >> 4;
    const int a   = blk & 15;
    const int t   = threadIdx.x;

    // ---- one-time staging: Fs^T, Ft^T (transpose via LDS), U, mask -------
    {
        const float4* fsp = (const float4*)(Fsrc + b * 2048);
        const float4* ftp = (const float4*)(Ftgt + b * 2048);
#pragma unroll
        for (int it = 0; it < 2; ++it) {
            const int k = t + it * 256;           // float4 = X[d][x0..x0+3]
            const int d = k >> 2, x0 = (k & 3) * 4;
            const float4 f = fsp[k];
            sFsT[(x0 + 0) * LS + d] = f.x;
            sFsT[(x0 + 1) * LS + d] = f.y;
            sFsT[(x0 + 2) * LS + d] = f.z;
            sFsT[(x0 + 3) * LS + d] = f.w;
            const float4 g = ftp[k];
            sFtT[(x0 + 0) * LS + d] = g.x;
            sFtT[(x0 + 1) * LS + d] = g.y;
            sFtT[(x0 + 2) * LS + d] = g.z;
            sFtT[(x0 + 3) * LS + d] = g.w;
        }
        if (t < 64)       ((float4*)sU)[t] = ((const float4*)(Usrc + b * 256))[t];
        else if (t < 128) ((float4*)sU)[t] = ((const float4*)(Utgt + b * 256))[t - 64];
        if (t < 120) smask[t] = (Asrc[b * 120 + t] > 0) && (Atgt[b * 120 + t] > 0);
    }

    // ---- S_l[u][j] = sum_i Fs[i][u] * W_l[i][j], W chunked over i ---------
    const int u  = t >> 4;
    const int jg = t & 15;          // owns j in {jg*4..+3} u {64+jg*4..+3}
    float acc1[8], acc2[8];
#pragma unroll
    for (int s = 0; s < 8; ++s) { acc1[s] = 0.f; acc2[s] = 0.f; }

    for (int i0 = 0; i0 < 128; i0 += CH) {
        // stage lam chunk rows (coalesced f4) and cols (128B-contig gather)
        const float4* r1 = (const float4*)(lam1 + i0 * 128);
        const float4* r2 = (const float4*)(lam2 + i0 * 128);
#pragma unroll
        for (int it = 0; it < 4; ++it) {
            const int k = t + it * 256;           // [0,1024) float4s
            const int il = k >> 5, j4 = k & 31;
            *(float4*)(&sRow1[il * LS + j4 * 4]) = r1[il * 32 + j4];
            *(float4*)(&sRow2[il * LS + j4 * 4]) = r2[il * 32 + j4];
        }
#pragma unroll
        for (int it = 0; it < 16; ++it) {
            const int k = t + it * 256;           // [0,4096)
            const int il = k & 31, j = k >> 5;
            sCol1[il * LS + j] = lam1[j * 128 + i0 + il];
            sCol2[il * LS + j] = lam2[j * 128 + i0 + il];
        }
        __syncthreads();                          // B1: staging ready

        // materialize W chunk: W[il][j] = relu(row + col)
#pragma unroll
        for (int g = 0; g < 4; ++g) {
            const int k = t + g * 256;            // [0,1024) f4-groups
            const int il = k >> 5, j4 = (k & 31) * 4;
            const float4 r = *(const float4*)(&sRow1[il * LS + j4]);
            const float4 c = *(const float4*)(&sCol1[il * LS + j4]);
            float4 w;
            w.x = fmaxf(r.x + c.x, 0.f);  w.y = fmaxf(r.y + c.y, 0.f);
            w.z = fmaxf(r.z + c.z, 0.f);  w.w = fmaxf(r.w + c.w, 0.f);
            *(float4*)(&sW1[il * LS + j4]) = w;
            const float4 r2v = *(const float4*)(&sRow2[il * LS + j4]);
            const float4 c2v = *(const float4*)(&sCol2[il * LS + j4]);
            float4 w2;
            w2.x = fmaxf(r2v.x + c2v.x, 0.f);  w2.y = fmaxf(r2v.y + c2v.y, 0.f);
            w2.z = fmaxf(r2v.z + c2v.z, 0.f);  w2.w = fmaxf(r2v.w + c2v.w, 0.f);
            *(float4*)(&sW2[il * LS + j4]) = w2;
        }
        __syncthreads();                          // B2: W ready

        // accumulate S over this chunk (reads sW + sFsT only)
#pragma unroll 8
        for (int il = 0; il < CH; ++il) {
            const float f1 = sFsT[u * LS + i0 + il];
            const float4 wA = *(const float4*)(&sW1[il * LS + jg * 4]);
            const float4 wB = *(const float4*)(&sW1[il * LS + 64 + jg * 4]);
            acc1[0] = fmaf(f1, wA.x, acc1[0]);  acc1[1] = fmaf(f1, wA.y, acc1[1]);
            acc1[2] = fmaf(f1, wA.z, acc1[2]);  acc1[3] = fmaf(f1, wA.w, acc1[3]);
            acc1[4] = fmaf(f1, wB.x, acc1[4]);  acc1[5] = fmaf(f1, wB.y, acc1[5]);
            acc1[6] = fmaf(f1, wB.z, acc1[6]);  acc1[7] = fmaf(f1, wB.w, acc1[7]);
            const float4 vA = *(const float4*)(&sW2[il * LS + jg * 4]);
            const float4 vB = *(const float4*)(&sW2[il * LS + 64 + jg * 4]);
            acc2[0] = fmaf(f1, vA.x, acc2[0]);  acc2[1] = fmaf(f1, vA.y, acc2[1]);
            acc2[2] = fmaf(f1, vA.z, acc2[2]);  acc2[3] = fmaf(f1, vA.w, acc2[3]);
            acc2[4] = fmaf(f1, vB.x, acc2[4]);  acc2[5] = fmaf(f1, vB.y, acc2[5]);
            acc2[6] = fmaf(f1, vB.z, acc2[6]);  acc2[7] = fmaf(f1, vB.w, acc2[7]);
        }
        __syncthreads();                          // B3: S reads done before re-stage
    }

    // write S to LDS
    *(float4*)(&sS1[u * LS + jg * 4])      = make_float4(acc1[0], acc1[1], acc1[2], acc1[3]);
    *(float4*)(&sS1[u * LS + 64 + jg * 4]) = make_float4(acc1[4], acc1[5], acc1[6], acc1[7]);
    *(float4*)(&sS2[u * LS + jg * 4])      = make_float4(acc2[0], acc2[1], acc2[2], acc2[3]);
    *(float4*)(&sS2[u * LS + 64 + jg * 4]) = make_float4(acc2[4], acc2[5], acc2[6], acc2[7]);
    __syncthreads();

    // ---- P tables: P_l[u][v] = sum_j S_l[u][j] * FtT[v][j];  Mp ----------
    {
        const int u2 = t >> 4, v = t & 15;
        float p1 = 0.f, p2 = 0.f;
#pragma unroll 8
        for (int j0 = 0; j0 < 128; j0 += 4) {
            const float4 ft = *(const float4*)(&sFtT[v * LS + j0]);
            const float4 s1 = *(const float4*)(&sS1[u2 * LS + j0]);
            const float4 s2 = *(const float4*)(&sS2[u2 * LS + j0]);
            p1 = fmaf(s1.x, ft.x, p1);  p2 = fmaf(s2.x, ft.x, p2);
            p1 = fmaf(s1.y, ft.y, p1);  p2 = fmaf(s2.y, ft.y, p2);
            p1 = fmaf(s1.z, ft.z, p1);  p2 = fmaf(s2.z, ft.z, p2);
            p1 = fmaf(s1.w, ft.w, p1);  p2 = fmaf(s2.w, ft.w, p2);
        }
        float mp = 0.f;
#pragma unroll
        for (int d = 0; d < 16; ++d)
            mp = fmaf(sU[(d << 4) | u2], sU[256 + ((d << 4) | v)], mp);
        sP1[u2 * TS + v] = p1;
        sP2[u2 * TS + v] = p2;
        sMp[t] = mp;                              // Mp[u][v] at (u<<4)|v
    }
    __syncthreads();

    // ---- fill rows r = a*16 + c; coalesced float4 stores -----------------
    const int j0c = (t & 63) << 2;
    const int p   = j0c >> 4;
    const bool condA = (a < p) && (smask[edge_idx(a, p)] != 0);
    float* outR = out + ((size_t)b << 16) + (a << 12);
#pragma unroll
    for (int rr = 0; rr < 4; ++rr) {
        const int c = (t >> 6) + (rr << 2);
        const int r = (a << 4) | c;
        const float cpart = sP1[a * TS + c] + sP2[p * TS + c];
        float4 vec;
        float* vv = (float*)&vec;
#pragma unroll
        for (int s = 0; s < 4; ++s) {
            const int j = j0c + s, q = j & 15;
            float x = 0.f;
            if (condA && (c < q) && (smask[edge_idx(c, q)] != 0))
                x = cpart + sP2[a * TS + q] + sP1[p * TS + q];
            if (r == j) x += sMp[r];
            vv[s] = x;
        }
        *(float4*)(outR + (c << 8) + j0c) = vec;
    }
}

extern "C" void kernel_launch(void* const* d_in, const int* in_sizes, int n_in,
                              void* d_out, int out_size, void* d_ws, size_t ws_size,
                              hipStream_t stream) {
    const int*   A_src = (const int*)d_in[0];
    const int*   A_tgt = (const int*)d_in[1];
    const float* F_src = (const float*)d_in[2];
    const float* F_tgt = (const float*)d_in[3];
    const float* U_src = (const float*)d_in[4];
    const float* U_tgt = (const float*)d_in[5];
    const float* lam1  = (const float*)d_in[6];
    const float* lam2  = (const float*)d_in[7];
    float* out = (float*)d_out;

    kOne<<<256, 256, 0, stream>>>(A_src, A_tgt, F_src, F_tgt,
                                  U_src, U_tgt, lam1, lam2, out);
}

// Round 8
// 85.105 us; speedup vs baseline: 1.0061x; 1.0061x over previous
//
#include <hip/hip_runtime.h>

// M[b,i,j] (16 x 256 x 256):
//   a=i>>4, c=i&15, p=j>>4, q=j&15
//   off-diag (a<p, c<q, edge(a,p) and edge(c,q) present in BOTH graphs):
//     M = P1[a,c] + P2[p,c] + P2[a,q] + P1[p,q]
//   diag (i==j): += Mp[a,c]
// P_l = F_src^T relu(lam_l+lam_l^T) F_tgt (16x16/batch), Mp = U_src^T U_tgt.
//
// SINGLE dispatch, grid 256 = (b, a), block 256 (1 block/CU).
// Per block (16x redundant per batch, but dispatch overhead ~10us >> exec):
//   W_l = relu(lam_l + lam_l^T), materialized in 64-row LDS chunks via
//     lam^T scatter-stage + in-place RMW with coalesced lam-row reads;
//   S_l = Fs^T W_l   (16x128, 4ux4j register tile, 128 threads per lambda);
//   P_l = S_l Ft^T   (16x16);  Mp = Us^T Ut;  fill 16 output rows.

#define LS 132   // padded stride (33 float4s): (132x+j)%32 = (4x+j)%32
#define TS 17    // P-table stride
#define CH 64    // W chunk rows

__device__ __forceinline__ int edge_idx(int a, int p) {
    // strict upper triangle of 16x16, row-major (triu_indices(16, k=1))
    return (a * (31 - a)) / 2 + (p - a - 1);
}

__global__ __launch_bounds__(256) void kOne(
    const int* __restrict__ Asrc, const int* __restrict__ Atgt,
    const float* __restrict__ Fsrc, const float* __restrict__ Ftgt,
    const float* __restrict__ Usrc, const float* __restrict__ Utgt,
    const float* __restrict__ lam1, const float* __restrict__ lam2,
    float* __restrict__ out)
{
    __shared__ float sW[2][CH * LS];        // W chunk per lambda [il][j]
    __shared__ float sFs[2048];             // Fs [i][u] natural (stride 16)
    __shared__ float sFtT[16 * LS];         // Ft^T [v][j]
    __shared__ float sS[2][16 * LS];        // S_l [u][j]
    __shared__ float sU[512];               // Us | Ut
    __shared__ float sP1[16 * TS], sP2[16 * TS], sMp[256];
    __shared__ int   smask[120];

    const int blk = blockIdx.x;
    const int b   = blk >> 4;
    const int a   = blk & 15;
    const int t   = threadIdx.x;

    // ---- one-time staging: Fs (natural), Ft^T (transpose), U, mask -------
    {
        const float4* fsp = (const float4*)(Fsrc + b * 2048);
        const float4* ftp = (const float4*)(Ftgt + b * 2048);
#pragma unroll
        for (int it = 0; it < 2; ++it) {
            const int k = t + it * 256;            // [0,512) float4s
            ((float4*)sFs)[k] = fsp[k];
            const int d = k >> 2, v0 = (k & 3) * 4;
            const float4 g = ftp[k];
            sFtT[(v0 + 0) * LS + d] = g.x;
            sFtT[(v0 + 1) * LS + d] = g.y;
            sFtT[(v0 + 2) * LS + d] = g.z;
            sFtT[(v0 + 3) * LS + d] = g.w;
        }
        if (t < 64)       ((float4*)sU)[t] = ((const float4*)(Usrc + b * 256))[t];
        else if (t < 128) ((float4*)sU)[t] = ((const float4*)(Utgt + b * 256))[t - 64];
        if (t < 120) smask[t] = (Asrc[b * 120 + t] > 0) && (Atgt[b * 120 + t] > 0);
    }

    // ---- S GEMM over two 64-row W chunks ---------------------------------
    const int lsel = t >> 7;                 // this thread's lambda
    const int tl   = t & 127;
    const int ug   = tl >> 5;                // u-tile = 4*ug .. +3
    const int jg   = tl & 31;                // j-tile = 4*jg .. +3
    const float* lamG[2] = { lam1, lam2 };
    float acc[4][4];
#pragma unroll
    for (int r = 0; r < 4; ++r)
#pragma unroll
        for (int s = 0; s < 4; ++s) acc[r][s] = 0.f;

    for (int i0 = 0; i0 < 128; i0 += CH) {
        // stage lam^T chunk: sW[l][il][j] = lam_l[j][i0+il]
        // (f4 global gather per row segment, conflict-free b32 LDS scatter)
#pragma unroll
        for (int it = 0; it < 16; ++it) {
            const int k  = t + it * 256;          // [0,4096)
            const int l  = k >> 11;
            const int kk = k & 2047;
            const int j  = kk & 127, g = kk >> 7; // il-group g: il = 4g+e
            const float4 f = ((const float4*)lamG[l])[j * 32 + (i0 >> 2) + g];
            sW[l][(4 * g + 0) * LS + j] = f.x;
            sW[l][(4 * g + 1) * LS + j] = f.y;
            sW[l][(4 * g + 2) * LS + j] = f.z;
            sW[l][(4 * g + 3) * LS + j] = f.w;
        }
        __syncthreads();                          // lam^T staged (+ first-iter F/U)

        // in-place RMW: sW[l][il][j] = relu(sW + lam_l[i0+il][j])
#pragma unroll
        for (int it = 0; it < 16; ++it) {
            const int k  = t + it * 256;          // [0,4096) f4-slots
            const int l  = k >> 11;
            const int kk = k & 2047;
            const int il = kk >> 5, jb = kk & 31;
            const float4 row = ((const float4*)lamG[l])[(i0 + il) * 32 + jb];
            float* wp = &sW[l][il * LS + 4 * jb];
            float4 w = *(float4*)wp;
            w.x = fmaxf(w.x + row.x, 0.f);
            w.y = fmaxf(w.y + row.y, 0.f);
            w.z = fmaxf(w.z + row.z, 0.f);
            w.w = fmaxf(w.w + row.w, 0.f);
            *(float4*)wp = w;
        }
        __syncthreads();                          // W chunk ready

        // accumulate S tile: acc[r][s] += Fs[i][4ug+r] * W[il][4jg+s]
        const float* sWl = sW[lsel];
#pragma unroll 8
        for (int il = 0; il < CH; ++il) {
            const float4 fs = *(const float4*)(&sFs[(i0 + il) * 16 + 4 * ug]);
            const float4 w  = *(const float4*)(&sWl[il * LS + 4 * jg]);
            acc[0][0] = fmaf(fs.x, w.x, acc[0][0]);
            acc[0][1] = fmaf(fs.x, w.y, acc[0][1]);
            acc[0][2] = fmaf(fs.x, w.z, acc[0][2]);
            acc[0][3] = fmaf(fs.x, w.w, acc[0][3]);
            acc[1][0] = fmaf(fs.y, w.x, acc[1][0]);
            acc[1][1] = fmaf(fs.y, w.y, acc[1][1]);
            acc[1][2] = fmaf(fs.y, w.z, acc[1][2]);
            acc[1][3] = fmaf(fs.y, w.w, acc[1][3]);
            acc[2][0] = fmaf(fs.z, w.x, acc[2][0]);
            acc[2][1] = fmaf(fs.z, w.y, acc[2][1]);
            acc[2][2] = fmaf(fs.z, w.z, acc[2][2]);
            acc[2][3] = fmaf(fs.z, w.w, acc[2][3]);
            acc[3][0] = fmaf(fs.w, w.x, acc[3][0]);
            acc[3][1] = fmaf(fs.w, w.y, acc[3][1]);
            acc[3][2] = fmaf(fs.w, w.z, acc[3][2]);
            acc[3][3] = fmaf(fs.w, w.w, acc[3][3]);
        }
        __syncthreads();                          // before next chunk overwrites sW
    }

    // write S tiles: sS[l][u][j]
#pragma unroll
    for (int r = 0; r < 4; ++r)
        *(float4*)(&sS[lsel][(4 * ug + r) * LS + 4 * jg]) =
            make_float4(acc[r][0], acc[r][1], acc[r][2], acc[r][3]);
    __syncthreads();

    // ---- P tables: P_l[u][v] = sum_j S_l[u][j] * FtT[v][j];  Mp ----------
    {
        const int u2 = t >> 4, v = t & 15;
        float p1 = 0.f, p2 = 0.f;
#pragma unroll 8
        for (int j0 = 0; j0 < 128; j0 += 4) {
            const float4 ft = *(const float4*)(&sFtT[v * LS + j0]);
            const float4 s1 = *(const float4*)(&sS[0][u2 * LS + j0]);
            const float4 s2 = *(const float4*)(&sS[1][u2 * LS + j0]);
            p1 = fmaf(s1.x, ft.x, p1);  p2 = fmaf(s2.x, ft.x, p2);
            p1 = fmaf(s1.y, ft.y, p1);  p2 = fmaf(s2.y, ft.y, p2);
            p1 = fmaf(s1.z, ft.z, p1);  p2 = fmaf(s2.z, ft.z, p2);
            p1 = fmaf(s1.w, ft.w, p1);  p2 = fmaf(s2.w, ft.w, p2);
        }
        float mp = 0.f;
#pragma unroll
        for (int d = 0; d < 16; ++d)
            mp = fmaf(sU[(d << 4) | u2], sU[256 + ((d << 4) | v)], mp);
        sP1[u2 * TS + v] = p1;
        sP2[u2 * TS + v] = p2;
        sMp[t] = mp;                              // Mp[u][v] at (u<<4)|v
    }
    __syncthreads();

    // ---- fill rows r = a*16 + c; coalesced float4 stores -----------------
    const int j0c = (t & 63) << 2;
    const int p   = j0c >> 4;
    const bool condA = (a < p) && (smask[edge_idx(a, p)] != 0);
    float* outR = out + ((size_t)b << 16) + (a << 12);
#pragma unroll
    for (int rr = 0; rr < 4; ++rr) {
        const int c = (t >> 6) + (rr << 2);
        const int r = (a << 4) | c;
        const float cpart = sP1[a * TS + c] + sP2[p * TS + c];
        float4 vec;
        float* vv = (float*)&vec;
#pragma unroll
        for (int s = 0; s < 4; ++s) {
            const int j = j0c + s, q = j & 15;
            float x = 0.f;
            if (condA && (c < q) && (smask[edge_idx(c, q)] != 0))
                x = cpart + sP2[a * TS + q] + sP1[p * TS + q];
            if (r == j) x += sMp[r];
            vv[s] = x;
        }
        *(float4*)(outR + (c << 8) + j0c) = vec;
    }
}

extern "C" void kernel_launch(void* const* d_in, const int* in_sizes, int n_in,
                              void* d_out, int out_size, void* d_ws, size_t ws_size,
                              hipStream_t stream) {
    const int*   A_src = (const int*)d_in[0];
    const int*   A_tgt = (const int*)d_in[1];
    const float* F_src = (const float*)d_in[2];
    const float* F_tgt = (const float*)d_in[3];
    const float* U_src = (const float*)d_in[4];
    const float* U_tgt = (const float*)d_in[5];
    const float* lam1  = (const float*)d_in[6];
    const float* lam2  = (const float*)d_in[7];
    float* out = (float*)d_out;

    kOne<<<256, 256, 0, stream>>>(A_src, A_tgt, F_src, F_tgt,
                                  U_src, U_tgt, lam1, lam2, out);
}

// Round 9
// 77.456 us; speedup vs baseline: 1.1055x; 1.0987x over previous
//
#include <hip/hip_runtime.h>

// M[b,i,j] (16 x 256 x 256):
//   a=i>>4, c=i&15, p=j>>4, q=j&15
//   off-diag (a<p, c<q, edge(a,p) and edge(c,q) present in BOTH graphs):
//     M = P1[a,c] + P2[p,c] + P2[a,q] + P1[p,q]
//   diag (i==j): += Mp[a,c]
// P_l = F_src^T relu(lam_l+lam_l^T) F_tgt (16x16/batch), Mp = U_src^T U_tgt.
//
// Best-measured structure (round 6, 77.6 us):
// kA: T_l = relu(lam+lam^T) F_tgt -> ws TRANSPOSED [b][l][v][d]
//     (grid 256 = b,lsel,islice; all-b128 inner loop).
// kB: P tables from ws (pure b128 LDS loop) + output fill (grid 256 = b,a).
// Session finding: total time is ~95% harness-fixed (256MB ws re-poison
// ~40us @ 84% HBM peak + restores + graph-node gaps); kernel exec ~3us.
// Single-dispatch variants (coop r5: 115.9, fat-block r7/r8: ~85) all lose.

#define LS 132   // padded stride: (132*x + d) % 32 = (4x+d)%32 -> <=2-way (free)
#define TS 17    // P-table stride

__device__ __forceinline__ int edge_idx(int a, int p) {
    // strict upper triangle of 16x16, row-major (triu_indices(16, k=1))
    return (a * (31 - a)) / 2 + (p - a - 1);
}

// ---------------------------------------------------------------------------
// kA: T[b][l][v][i] = sum_j relu(lam[i][j]+lam[j][i]) * Ftgt[b][j][v]
// grid 256: b = blk>>4, lsel = (blk>>3)&1, i0 = (blk&7)*16
// ---------------------------------------------------------------------------
__global__ __launch_bounds__(256) void kA(
    const float* __restrict__ Ftgt,
    const float* __restrict__ lam1, const float* __restrict__ lam2,
    float* __restrict__ ws)
{
    __shared__ float sRow[16 * LS];   // lam rows  [il][j]
    __shared__ float sCol[16 * LS];   // lam cols  [il][j]
    __shared__ float sFtT[16 * LS];   // Ft^T      [v][j]

    const int blk  = blockIdx.x;
    const int b    = blk >> 4;
    const int lsel = (blk >> 3) & 1;
    const int i0   = (blk & 7) << 4;
    const int t    = threadIdx.x;

    const float* lam = lsel ? lam2 : lam1;

    // rows: sRow[il*LS + j] = lam[(i0+il)*128 + j]   (float4 coalesced)
    const float4* rp = (const float4*)(lam + i0 * 128);
#pragma unroll
    for (int it = 0; it < 2; ++it) {
        const int k = t + it * 256;              // [0,512) float4s
        const int il = k >> 5, j4 = k & 31;
        *(float4*)(&sRow[il * LS + j4 * 4]) = rp[il * 32 + j4];
    }
    // cols: sCol[il*LS + j] = lam[j*128 + i0+il]    (64B-contig gather, L2-hot)
#pragma unroll
    for (int it = 0; it < 8; ++it) {
        const int k = t + it * 256;              // [0,2048)
        const int il = k & 15, j = k >> 4;
        sCol[il * LS + j] = lam[j * 128 + i0 + il];
    }
    // FtT: sFtT[v*LS + j] = Ftgt[b][j][v]          (transpose via LDS)
    const float4* fp = (const float4*)(Ftgt + b * 2048);
#pragma unroll
    for (int it = 0; it < 2; ++it) {
        const int k = t + it * 256;              // float4 = Ft[j][v0..v0+3]
        const int j = k >> 2, v0 = (k & 3) * 4;
        const float4 f = fp[k];
        sFtT[(v0 + 0) * LS + j] = f.x;
        sFtT[(v0 + 1) * LS + j] = f.y;
        sFtT[(v0 + 2) * LS + j] = f.z;
        sFtT[(v0 + 3) * LS + j] = f.w;
    }
    __syncthreads();

    const int v = t >> 4, il = t & 15;           // il fast -> coalesced ws write
    float acc = 0.f;
#pragma unroll 8
    for (int j0 = 0; j0 < 128; j0 += 4) {
        const float4 r = *(const float4*)(&sRow[il * LS + j0]);
        const float4 c = *(const float4*)(&sCol[il * LS + j0]);
        const float4 f = *(const float4*)(&sFtT[v * LS + j0]);
        acc = fmaf(fmaxf(r.x + c.x, 0.f), f.x, acc);
        acc = fmaf(fmaxf(r.y + c.y, 0.f), f.y, acc);
        acc = fmaf(fmaxf(r.z + c.z, 0.f), f.z, acc);
        acc = fmaf(fmaxf(r.w + c.w, 0.f), f.w, acc);
    }
    // ws: T[b][l][v][d] at ((b*2+l)*16 + v)*128 + i0 + il
    ws[((b * 2 + lsel) * 16 + v) * 128 + i0 + il] = acc;
}

// ---------------------------------------------------------------------------
// kB: per-block P1/P2/Mp tables (redundant across the 16 row-groups of a
// batch — cheap, fully parallel), then fill 16 output rows.
// grid 256: b = blk>>4, a = blk&15.
// ---------------------------------------------------------------------------
__global__ __launch_bounds__(256) void kB(
    const int* __restrict__ Asrc, const int* __restrict__ Atgt,
    const float* __restrict__ Fsrc,
    const float* __restrict__ Usrc, const float* __restrict__ Utgt,
    const float* __restrict__ ws, float* __restrict__ out)
{
    __shared__ float sT1[16 * LS];   // T1^T [v][d]
    __shared__ float sT2[16 * LS];   // T2^T [v][d]
    __shared__ float sFs[16 * LS];   // Fs^T [u][d]
    __shared__ float sU[512];        // Us | Ut
    __shared__ float sP1[16 * TS], sP2[16 * TS], sMp[256];
    __shared__ int   smask[120];

    const int blk = blockIdx.x;
    const int b   = blk >> 4;
    const int a   = blk & 15;
    const int t   = threadIdx.x;

    // T tables, already [v][d] in ws: straight float4 copy into padded LDS
    const float4* T1g = (const float4*)(ws + (b * 2 + 0) * 2048);
    const float4* T2g = (const float4*)(ws + (b * 2 + 1) * 2048);
#pragma unroll
    for (int it = 0; it < 2; ++it) {
        const int k = t + it * 256;              // [0,512) float4s
        const int v = k >> 5, d4 = (k & 31) * 4;
        *(float4*)(&sT1[v * LS + d4]) = T1g[k];
        *(float4*)(&sT2[v * LS + d4]) = T2g[k];
    }
    // FsT: sFs[u*LS + d] = Fsrc[b][d][u]          (transpose via LDS)
    const float4* fp = (const float4*)(Fsrc + b * 2048);
#pragma unroll
    for (int it = 0; it < 2; ++it) {
        const int k = t + it * 256;
        const int d = k >> 2, u0 = (k & 3) * 4;
        const float4 f = fp[k];
        sFs[(u0 + 0) * LS + d] = f.x;
        sFs[(u0 + 1) * LS + d] = f.y;
        sFs[(u0 + 2) * LS + d] = f.z;
        sFs[(u0 + 3) * LS + d] = f.w;
    }
    if (t < 64)       ((float4*)sU)[t] = ((const float4*)(Usrc + b * 256))[t];
    else if (t < 128) ((float4*)sU)[t] = ((const float4*)(Utgt + b * 256))[t - 64];
    if (t < 120) smask[t] = (Asrc[b * 120 + t] > 0) && (Atgt[b * 120 + t] > 0);
    __syncthreads();

    // tables: P_l[u][v] = sum_d FsT[u][d] * Tlt[v][d];  Mp[u][v]
    {
        const int u = t >> 4, v = t & 15;
        float p1 = 0.f, p2 = 0.f;
#pragma unroll 8
        for (int d0 = 0; d0 < 128; d0 += 4) {
            const float4 fs = *(const float4*)(&sFs[u * LS + d0]);
            const float4 t1 = *(const float4*)(&sT1[v * LS + d0]);
            const float4 t2 = *(const float4*)(&sT2[v * LS + d0]);
            p1 = fmaf(fs.x, t1.x, p1);  p2 = fmaf(fs.x, t2.x, p2);
            p1 = fmaf(fs.y, t1.y, p1);  p2 = fmaf(fs.y, t2.y, p2);
            p1 = fmaf(fs.z, t1.z, p1);  p2 = fmaf(fs.z, t2.z, p2);
            p1 = fmaf(fs.w, t1.w, p1);  p2 = fmaf(fs.w, t2.w, p2);
        }
        float mp = 0.f;
#pragma unroll
        for (int d = 0; d < 16; ++d)
            mp = fmaf(sU[(d << 4) | u], sU[256 + ((d << 4) | v)], mp);
        sP1[u * TS + v] = p1;
        sP2[u * TS + v] = p2;
        sMp[t] = mp;                              // Mp[u][v] at (u<<4)|v
    }
    __syncthreads();

    // fill rows r = a*16 + c; coalesced float4 stores
    const int j0 = (t & 63) << 2;
    const int p  = j0 >> 4;
    const bool condA = (a < p) && (smask[edge_idx(a, p)] != 0);
    float* outR = out + ((size_t)b << 16) + (a << 12);
#pragma unroll
    for (int rr = 0; rr < 4; ++rr) {
        const int c = (t >> 6) + (rr << 2);
        const int r = (a << 4) | c;
        const float cpart = sP1[a * TS + c] + sP2[p * TS + c];
        float4 vec;
        float* vv = (float*)&vec;
#pragma unroll
        for (int s = 0; s < 4; ++s) {
            const int j = j0 + s, q = j & 15;
            float x = 0.f;
            if (condA && (c < q) && (smask[edge_idx(c, q)] != 0))
                x = cpart + sP2[a * TS + q] + sP1[p * TS + q];
            if (r == j) x += sMp[r];
            vv[s] = x;
        }
        *(float4*)(outR + (c << 8) + j0) = vec;
    }
}

extern "C" void kernel_launch(void* const* d_in, const int* in_sizes, int n_in,
                              void* d_out, int out_size, void* d_ws, size_t ws_size,
                              hipStream_t stream) {
    const int*   A_src = (const int*)d_in[0];
    const int*   A_tgt = (const int*)d_in[1];
    const float* F_src = (const float*)d_in[2];
    const float* F_tgt = (const float*)d_in[3];
    const float* U_src = (const float*)d_in[4];
    const float* U_tgt = (const float*)d_in[5];
    const float* lam1  = (const float*)d_in[6];
    const float* lam2  = (const float*)d_in[7];
    float* out = (float*)d_out;
    float* ws  = (float*)d_ws;   // 65536 floats = 256 KB used

    kA<<<256, 256, 0, stream>>>(F_tgt, lam1, lam2, ws);
    kB<<<256, 256, 0, stream>>>(A_src, A_tgt, F_src, U_src, U_tgt, ws, out);
}